// Round 6
// baseline (797.682 us; speedup 1.0000x reference)
//
#include <hip/hip_runtime.h>
#include <math.h>

typedef __attribute__((ext_vector_type(8))) short short8;
typedef __attribute__((ext_vector_type(4))) float floatx4;
typedef unsigned short u16;

#define DEVFN static __device__ __forceinline__

DEVFN float b2f(u16 u) { union { unsigned int i; float f; } x; x.i = ((unsigned int)u) << 16; return x.f; }
DEVFN u16 f2b(float f) {
    union { float f; unsigned int i; } x; x.f = f;
    unsigned int r = (x.i + 0x7fffu + ((x.i >> 16) & 1u)) >> 16;
    return (u16)r;
}

DEVFN floatx4 mfma_bf16(short8 a, short8 b, floatx4 c) {
    return __builtin_amdgcn_mfma_f32_16x16x32_bf16(a, b, c, 0, 0, 0);
}

// ---------------- dtype detect: head_mask == 1.0 exactly.  bf16 word0 = 0x3F803F80, fp32 = 0x3F800000
__global__ void detect_k(const unsigned int* __restrict__ hm, int* __restrict__ flag) {
    if (threadIdx.x == 0) *flag = ((hm[0] & 0xFFFFu) != 0u) ? 1 : 0;  // 1 = inputs are bf16
}

// ---------------- canonicalize input -> bf16 buffer ----------------
__global__ void conv_k(const void* __restrict__ src, u16* __restrict__ dst, int n,
                       const int* __restrict__ flag) {
    int i = blockIdx.x * 256 + threadIdx.x;
    if (i < n) dst[i] = (*flag) ? ((const u16*)src)[i] : f2b(((const float*)src)[i]);
}

// ---------------- merged small-tensor converter (12 segments, layout = 'smalls') ----------------
struct SmallSrc { const void* p[12]; };
__global__ void convsmall_k(SmallSrc srcs, u16* __restrict__ dst, const int* __restrict__ flag) {
    const int offs[13] = {0, 1024, 2048, 3072, 4096, 8192, 9216, 10240, 11264, 12288, 13312, 17408, 17424};
    int i = blockIdx.x * 256 + threadIdx.x;
    if (i >= 17424) return;
    int seg = 0;
    while (i >= offs[seg + 1]) seg++;
    int off = i - offs[seg];
    const void* s = srcs.p[seg];
    dst[i] = (*flag) ? ((const u16*)s)[off] : f2b(((const float*)s)[off]);
}

// ---------------- fused convert + transpose: src [R,C] -> dst bf16 [C,R] ----------------
__global__ void convT_k(const void* __restrict__ src, u16* __restrict__ dst, int R, int C,
                        const int* __restrict__ flag) {
    __shared__ u16 t[32][33];
    int bx = blockIdx.x * 32, by = blockIdx.y * 32;
    int tx = threadIdx.x, ty = threadIdx.y;  // 32 x 8
    if (*flag) {
        const u16* s = (const u16*)src;
        for (int j = ty; j < 32; j += 8) t[j][tx] = s[(size_t)(by + j) * C + bx + tx];
    } else {
        const float* s = (const float*)src;
        for (int j = ty; j < 32; j += 8) t[j][tx] = f2b(s[(size_t)(by + j) * C + bx + tx]);
    }
    __syncthreads();
    for (int j = ty; j < 32; j += 8) dst[(size_t)(bx + j) * R + by + tx] = t[tx][j];
}

// ---------------- GEMM: C = A[M,K] @ Bt[N,K]^T + bias (canonical bf16) ----------------
// MODE 0: QKV concat store (N=3072): q,k -> [bh][s][d]; v (cols>=2048) -> TRANSPOSED [bh][d][s]
// MODE 1: out bf16 [M,N] = x + resid(bf16)[M,N]
// MODE 2: out bf16 [M,N] = gelu_exact(x)
template <int MODE>
__global__ __launch_bounds__(256, 2) void gemm_k(
    const u16* __restrict__ A, const u16* __restrict__ Bt,
    const u16* __restrict__ bias, const u16* __restrict__ resid,
    u16* __restrict__ Cout, int M, int N, int K) {
    __shared__ __align__(16) u16 As[128 * 40];
    __shared__ __align__(16) u16 Bs[128 * 40];
    const int m0 = blockIdx.x * 128, n0 = blockIdx.y * 128;
    const int tid = threadIdx.x;
    const int wave = tid >> 6, lane = tid & 63;
    const int wm = (wave >> 1) * 64, wn = (wave & 1) * 64;
    const int c = lane & 15, quad = lane >> 4;
    floatx4 acc[4][4] = {};
    for (int k0 = 0; k0 < K; k0 += 32) {
        __syncthreads();
        {
            int ch = tid, row = ch >> 2, kc = ch & 3;
            *(uint4*)&As[row * 40 + kc * 8] = *(const uint4*)&A[(size_t)(m0 + row) * K + k0 + kc * 8];
            *(uint4*)&Bs[row * 40 + kc * 8] = *(const uint4*)&Bt[(size_t)(n0 + row) * K + k0 + kc * 8];
            ch = tid + 256; row = ch >> 2; kc = ch & 3;
            *(uint4*)&As[row * 40 + kc * 8] = *(const uint4*)&A[(size_t)(m0 + row) * K + k0 + kc * 8];
            *(uint4*)&Bs[row * 40 + kc * 8] = *(const uint4*)&Bt[(size_t)(n0 + row) * K + k0 + kc * 8];
        }
        __syncthreads();
        short8 af[4], bf[4];
#pragma unroll
        for (int mi = 0; mi < 4; mi++) af[mi] = *(const short8*)&As[(wm + mi * 16 + c) * 40 + quad * 8];
#pragma unroll
        for (int ni = 0; ni < 4; ni++) bf[ni] = *(const short8*)&Bs[(wn + ni * 16 + c) * 40 + quad * 8];
#pragma unroll
        for (int mi = 0; mi < 4; mi++)
#pragma unroll
            for (int ni = 0; ni < 4; ni++)
                acc[mi][ni] = mfma_bf16(af[mi], bf[ni], acc[mi][ni]);
    }
#pragma unroll
    for (int ni = 0; ni < 4; ni++) {
        int col = n0 + wn + ni * 16 + c;
        float bv = b2f(bias[col]);
#pragma unroll
        for (int mi = 0; mi < 4; mi++) {
            int row0 = m0 + wm + mi * 16 + quad * 4;
            if (MODE == 0 && (col >> 10) == 2) {
                // V transposed store: vt[bh][d][s], 4 consecutive s -> ushort4
                int rem = col & 1023, h = rem >> 6, d = rem & 63;
                int bb = row0 >> 10, s = row0 & 1023;
                ushort4 pv;
                pv.x = f2b(acc[mi][ni][0] + bv); pv.y = f2b(acc[mi][ni][1] + bv);
                pv.z = f2b(acc[mi][ni][2] + bv); pv.w = f2b(acc[mi][ni][3] + bv);
                *(ushort4*)&Cout[(size_t)2 * 4194304 + ((size_t)(bb * 16 + h) * 64 + d) * 1024 + s] = pv;
            } else {
#pragma unroll
                for (int r = 0; r < 4; r++) {
                    int row = row0 + r;
                    float x = acc[mi][ni][r] + bv;
                    size_t idx = (size_t)row * N + col;
                    if (MODE == 0) {
                        int which = col >> 10, rem = col & 1023, h = rem >> 6, d = rem & 63;
                        int bb = row >> 10, s = row & 1023;
                        Cout[(size_t)which * 4194304 + ((size_t)(bb * 16 + h) * 1024 + s) * 64 + d] = f2b(x);
                    } else if (MODE == 1) {
                        Cout[idx] = f2b(x + b2f(resid[idx]));
                    } else {
                        float gl = 0.5f * x * (1.0f + erff(x * 0.70710678118654752f));
                        Cout[idx] = f2b(gl);
                    }
                }
            }
        }
    }
}

// ---------------- flash attention with relative_key_query bias (canonical bf16) ----------------
// q,k: [bh][s][64]; vt: [bh][d][s] (pre-transposed); de: [2047][64]; ctx out: [B,S,H,D]
// LDS 52KB -> 3 blocks/CU. K/V fragments batched into registers at tile top; de band staged in LDS.
__global__ __launch_bounds__(256, 3) void attn_k(
    const u16* __restrict__ q, const u16* __restrict__ k, const u16* __restrict__ vt,
    const u16* __restrict__ de, const u16* __restrict__ amask, const u16* __restrict__ hmask,
    u16* __restrict__ ctx) {
    __shared__ __align__(16) u16 DeP[128 * 72];  // de band [row][64+8]  ∪  Ps [64][72] (phase-disjoint)
    __shared__ __align__(16) u16 QDT[128 * 68];  // qd band transposed [u][l], stride 68
    __shared__ __align__(16) u16 KDT[128 * 68];  // kd band transposed [u][r], stride 68
    const int bh = blockIdx.y, b = bh >> 4, h = bh & 15;
    const int L0 = blockIdx.x * 64;
    const int tid = threadIdx.x, wave = tid >> 6, lane = tid & 63;
    const int c = lane & 15, quad = lane >> 4;
    u16* Ps = DeP;

    const size_t qrow = ((size_t)bh * 1024 + L0 + wave * 16 + c) * 64;
    const short8 qf0 = *(const short8*)&q[qrow + quad * 8];
    const short8 qf1 = *(const short8*)&q[qrow + 32 + quad * 8];
    const u16* kbase = k + (size_t)bh * 65536;
    const u16* vbase = vt + (size_t)bh * 65536;

    floatx4 O[4] = {};
    float mrow[4] = {-1e30f, -1e30f, -1e30f, -1e30f};
    float lrow[4] = {0.f, 0.f, 0.f, 0.f};
    const float hm = b2f(hmask[h]);

    for (int rt = 0; rt < 16; rt++) {
        const int R0 = rt * 64;
        const int t0 = L0 - R0 + 960;
        // ---- batched register loads: K B-frags (S phase), V B-frags (PV phase), kd A-frag ----
        short8 kB0[4], kB1[4], vB0[4], vB1[4];
#pragma unroll
        for (int nt = 0; nt < 4; nt++) {
            const u16* kr = kbase + (size_t)(R0 + nt * 16 + c) * 64 + quad * 8;
            kB0[nt] = *(const short8*)kr;
            kB1[nt] = *(const short8*)(kr + 32);
        }
#pragma unroll
        for (int dt = 0; dt < 4; dt++) {
            const u16* vr = vbase + (size_t)(dt * 16 + c) * 1024 + R0 + quad * 8;
            vB0[dt] = *(const short8*)vr;
            vB1[dt] = *(const short8*)(vr + 32);
        }
        const u16* kar = kbase + (size_t)(R0 + wave * 16 + c) * 64 + quad * 8;
        const short8 ka0 = *(const short8*)kar;
        const short8 ka1 = *(const short8*)(kar + 32);

        __syncthreads();  // (a) prev-tile PV done reading Ps before De overwrites region
        // ---- stage de band -> LDS (padded stride 72) ----
#pragma unroll
        for (int i = 0; i < 4; i++) {
            int ch = tid + i * 256, row = ch >> 3, kc = ch & 7;
            int tr = t0 + row; if (tr > 2046) tr = 2046;  // only u<=126 used; clamp avoids OOB
            *(uint4*)&DeP[row * 72 + kc * 8] = *(const uint4*)&de[(size_t)tr * 64 + kc * 8];
        }
        __syncthreads();  // (b) de staged
        // ---- qd/kd band MFMAs, write transposed [u][l/r] ----
#pragma unroll
        for (int ut = 0; ut < 8; ut++) {
            const short8 df0 = *(const short8*)&DeP[(ut * 16 + c) * 72 + quad * 8];
            const short8 df1 = *(const short8*)&DeP[(ut * 16 + c) * 72 + 32 + quad * 8];
            floatx4 aq = {}, ak = {};
            aq = mfma_bf16(qf0, df0, aq); aq = mfma_bf16(qf1, df1, aq);
            ak = mfma_bf16(ka0, df0, ak); ak = mfma_bf16(ka1, df1, ak);
            ushort4 wq, wk;
            wq.x = f2b(aq[0]); wq.y = f2b(aq[1]); wq.z = f2b(aq[2]); wq.w = f2b(aq[3]);
            wk.x = f2b(ak[0]); wk.y = f2b(ak[1]); wk.z = f2b(ak[2]); wk.w = f2b(ak[3]);
            int base = (ut * 16 + c) * 68 + wave * 16 + quad * 4;
            *(ushort4*)&QDT[base] = wq;
            *(ushort4*)&KDT[base] = wk;
        }
        __syncthreads();  // (c) bands ready; De now dead -> Ps may overwrite
        // ---- S tile (K frags from regs) + bias gather + mask ----
        float sv[4][4];
#pragma unroll
        for (int nt = 0; nt < 4; nt++) {
            floatx4 a = {};
            a = mfma_bf16(qf0, kB0[nt], a);
            a = mfma_bf16(qf1, kB1[nt], a);
            int ri = nt * 16 + c;
            float am = b2f(amask[b * 1024 + R0 + ri]);
#pragma unroll
            for (int r = 0; r < 4; r++) {
                int li = wave * 16 + quad * 4 + r;
                int u = li - ri + 63;  // in [0,126]
                float biasv = b2f(QDT[u * 68 + li]) + b2f(KDT[u * 68 + ri]);
                sv[nt][r] = (a[r] + biasv) * 0.125f + am;
            }
        }
        // ---- online softmax (rows spread over the 16 lanes of each quad-group) ----
#pragma unroll
        for (int r = 0; r < 4; r++) {
            float rmax = fmaxf(fmaxf(sv[0][r], sv[1][r]), fmaxf(sv[2][r], sv[3][r]));
#pragma unroll
            for (int m = 1; m < 16; m <<= 1) rmax = fmaxf(rmax, __shfl_xor(rmax, m, 64));
            float mnew = fmaxf(mrow[r], rmax);
            float alpha = __expf(mrow[r] - mnew);
            float ps = 0.f;
#pragma unroll
            for (int nt = 0; nt < 4; nt++) { float p = __expf(sv[nt][r] - mnew); sv[nt][r] = p; ps += p; }
#pragma unroll
            for (int m = 1; m < 16; m <<= 1) ps += __shfl_xor(ps, m, 64);
            lrow[r] = lrow[r] * alpha + ps;
            mrow[r] = mnew;
            O[0][r] *= alpha; O[1][r] *= alpha; O[2][r] *= alpha; O[3][r] *= alpha;
        }
        // ---- write P (overlays dead De region) ----
#pragma unroll
        for (int nt = 0; nt < 4; nt++)
#pragma unroll
            for (int r = 0; r < 4; r++)
                Ps[(wave * 16 + quad * 4 + r) * 72 + nt * 16 + c] = f2b(sv[nt][r]);
        __syncthreads();  // (d) P ready
        // ---- O += P @ V (V frags from regs) ----
        {
            const short8 pa0 = *(const short8*)&Ps[(wave * 16 + c) * 72 + quad * 8];
            const short8 pa1 = *(const short8*)&Ps[(wave * 16 + c) * 72 + 32 + quad * 8];
#pragma unroll
            for (int dt = 0; dt < 4; dt++) {
                O[dt] = mfma_bf16(pa0, vB0[dt], O[dt]);
                O[dt] = mfma_bf16(pa1, vB1[dt], O[dt]);
            }
        }
    }
    // epilogue: ctx[b, s, h, d]
#pragma unroll
    for (int r = 0; r < 4; r++) {
        float inv = hm / lrow[r];
        int s = L0 + wave * 16 + quad * 4 + r;
#pragma unroll
        for (int dt = 0; dt < 4; dt++)
            ctx[(((size_t)b * 1024 + s) * 16 + h) * 64 + dt * 16 + c] = f2b(O[dt][r] * inv);
    }
}

// ---------------- LayerNorm over 1024 bf16 -> bf16 (FINAL: d_out, dtype per flag) ----------------
template <int FINAL>
__global__ __launch_bounds__(256) void ln_k(const u16* __restrict__ x, const u16* __restrict__ g,
                                            const u16* __restrict__ bb, void* __restrict__ out,
                                            const int* __restrict__ flag) {
    const int row = blockIdx.x, tid = threadIdx.x;
    const u16* xr = x + (size_t)row * 1024;
    float vv[4];
#pragma unroll
    for (int j = 0; j < 4; j++) vv[j] = b2f(xr[tid * 4 + j]);
    float s = vv[0] + vv[1] + vv[2] + vv[3];
    float ss = vv[0] * vv[0] + vv[1] * vv[1] + vv[2] * vv[2] + vv[3] * vv[3];
#pragma unroll
    for (int m = 1; m < 64; m <<= 1) { s += __shfl_xor(s, m, 64); ss += __shfl_xor(ss, m, 64); }
    __shared__ float red[8];
    int wave = tid >> 6, lane = tid & 63;
    if (lane == 0) { red[wave] = s; red[wave + 4] = ss; }
    __syncthreads();
    s = red[0] + red[1] + red[2] + red[3];
    ss = red[4] + red[5] + red[6] + red[7];
    float mu = s * (1.f / 1024.f);
    float var = ss * (1.f / 1024.f) - mu * mu;
    float rs = rsqrtf(var + 1e-12f);
    const int out_bf16 = FINAL ? *flag : 1;
#pragma unroll
    for (int j = 0; j < 4; j++) {
        int idx = tid * 4 + j;
        float val = (vv[j] - mu) * rs * b2f(g[idx]) + b2f(bb[idx]);
        if (out_bf16) ((u16*)out)[(size_t)row * 1024 + idx] = f2b(val);
        else          ((float*)out)[(size_t)row * 1024 + idx] = val;
    }
}

extern "C" void kernel_launch(void* const* d_in, const int* in_sizes, int n_in,
                              void* d_out, int out_size, void* d_ws, size_t ws_size,
                              hipStream_t stream) {
    (void)in_sizes; (void)n_in; (void)out_size;
    const void* hidden = d_in[0];
    const void* amaskI = d_in[1];
    const void* hmaskI = d_in[2];
    const void* Wq = d_in[3];  const void* bq = d_in[4];
    const void* Wk = d_in[5];  const void* bk = d_in[6];
    const void* Wv = d_in[7];  const void* bv = d_in[8];
    const void* de = d_in[9];
    const void* Wo = d_in[10]; const void* bo = d_in[11];
    const void* ln1g = d_in[12]; const void* ln1b = d_in[13];
    const void* Wi = d_in[14]; const void* bi = d_in[15];
    const void* Wo2 = d_in[16]; const void* bo2 = d_in[17];
    const void* ln2g = d_in[18]; const void* ln2b = d_in[19];

    const size_t MB = 1048576;
    char* ws = (char*)d_ws;
    const bool big = (ws_size >= (size_t)70 * MB);

    u16* wsQKV  = (u16*)(ws);                      // Q@0, K@+4M elts, V^T@+8M elts
    u16* wsCtx  = (u16*)(ws + 24 * MB);
    u16* wsInter= (u16*)(ws);                      // full path: 32MB over QKV+Ctx
    u16* cHid   = (u16*)(ws + 32 * MB);
    u16* cWo2T  = (u16*)(ws + 32 * MB);            // after cHid dead
    u16* preLN  = big ? (u16*)(ws + 40 * MB) : (u16*)(ws + 16 * MB);
    u16* attnO  = big ? (u16*)(ws + 48 * MB) : (u16*)(ws + 24 * MB);
    u16* cQKVT  = big ? (u16*)(ws + 56 * MB) : (u16*)(ws + 40 * MB);
    u16* cWoT   = big ? (u16*)(ws + 62 * MB) : (u16*)(ws + 46 * MB);
    u16* cWiT   = cQKVT;                           // 8MB over cQKVT+cWoT after both dead
    u16* cDe    = big ? (u16*)(ws + 64 * MB) : (u16*)(ws + 48 * MB);
    u16* smalls = (u16*)((char*)cDe + 262144);
    int* flag   = (int*)((char*)smalls + 65536);

    u16* s_bqkv = smalls;                 // 3072
    u16* s_bo   = smalls + 3072;          // 1024
    u16* s_bi   = smalls + 4096;          // 4096
    u16* s_bo2  = smalls + 8192;          // 1024
    u16* s_l1g  = smalls + 9216, *s_l1b = smalls + 10240;
    u16* s_l2g  = smalls + 11264, *s_l2b = smalls + 12288;
    u16* s_am   = smalls + 13312;         // 4096
    u16* s_hm   = smalls + 17408;         // 16

    detect_k<<<1, 64, 0, stream>>>((const unsigned int*)hmaskI, flag);

    auto conv = [&](const void* src, u16* dst, int n) {
        conv_k<<<(n + 255) / 256, 256, 0, stream>>>(src, dst, n, flag);
    };
    auto convT = [&](const void* src, u16* dst, int R, int C) {
        convT_k<<<dim3(C / 32, R / 32), dim3(32, 8), 0, stream>>>(src, dst, R, C, flag);
    };

    conv(hidden, cHid, 4194304);
    convT(Wq, cQKVT, 1024, 1024);
    convT(Wk, cQKVT + 1048576, 1024, 1024);
    convT(Wv, cQKVT + 2097152, 1024, 1024);
    convT(Wo, cWoT, 1024, 1024);
    conv(de, cDe, 2047 * 64);
    {
        SmallSrc st;
        st.p[0] = bq;   st.p[1] = bk;   st.p[2] = bv;   st.p[3] = bo;
        st.p[4] = bi;   st.p[5] = bo2;  st.p[6] = ln1g; st.p[7] = ln1b;
        st.p[8] = ln2g; st.p[9] = ln2b; st.p[10] = amaskI; st.p[11] = hmaskI;
        convsmall_k<<<(17424 + 255) / 256, 256, 0, stream>>>(st, smalls, flag);
    }

    // fused QKV projection -> Q,K [bh][s][d]; V^T [bh][d][s]
    gemm_k<0><<<dim3(32, 24), 256, 0, stream>>>(cHid, cQKVT, s_bqkv, nullptr, wsQKV, 4096, 3072, 1024);

    // attention -> ctx [B,S,H,D]
    attn_k<<<dim3(16, 64), 256, 0, stream>>>(wsQKV, wsQKV + 4194304, wsQKV + 8388608,
                                             cDe, s_am, s_hm, wsCtx);

    // ctx @ Wo + bo + hidden -> preLN
    gemm_k<1><<<dim3(32, 8), 256, 0, stream>>>(wsCtx, cWoT, s_bo, cHid, preLN, 4096, 1024, 1024);

    // FF weights into now-dead regions
    convT(Wi, cWiT, 1024, 4096);    // WiT [4096,1024]
    convT(Wo2, cWo2T, 4096, 1024);  // Wo2T [1024,4096]

    // LN1 -> attnO
    ln_k<0><<<4096, 256, 0, stream>>>(preLN, s_l1g, s_l1b, attnO, flag);

    if (big) {
        gemm_k<2><<<dim3(32, 32), 256, 0, stream>>>(attnO, cWiT, s_bi, nullptr, wsInter, 4096, 4096, 1024);
        gemm_k<1><<<dim3(32, 8), 256, 0, stream>>>(wsInter, cWo2T, s_bo2, attnO, preLN, 4096, 1024, 4096);
    } else {
        u16* strip = (u16*)(ws);  // 2048x4096 bf16 = 16MB over dead Q|K
        for (int s = 0; s < 2; s++) {
            const u16* aoff = attnO + (size_t)s * 2048 * 1024;
            gemm_k<2><<<dim3(16, 32), 256, 0, stream>>>(aoff, cWiT, s_bi, nullptr, strip, 2048, 4096, 1024);
            gemm_k<1><<<dim3(16, 8), 256, 0, stream>>>(strip, cWo2T, s_bo2, aoff,
                                                       preLN + (size_t)s * 2048 * 1024, 2048, 1024, 4096);
        }
    }

    // LN2 -> d_out (dtype per flag)
    ln_k<1><<<4096, 256, 0, stream>>>(preLN, s_l2g, s_l2b, d_out, flag);
}

// Round 7
// 532.790 us; speedup vs baseline: 1.4972x; 1.4972x over previous
//
#include <hip/hip_runtime.h>
#include <math.h>

typedef __attribute__((ext_vector_type(8))) short short8;
typedef __attribute__((ext_vector_type(4))) float floatx4;
typedef unsigned short u16;

#define DEVFN static __device__ __forceinline__

DEVFN float b2f(u16 u) { union { unsigned int i; float f; } x; x.i = ((unsigned int)u) << 16; return x.f; }
DEVFN u16 f2b(float f) {
    union { float f; unsigned int i; } x; x.f = f;
    unsigned int r = (x.i + 0x7fffu + ((x.i >> 16) & 1u)) >> 16;
    return (u16)r;
}

DEVFN floatx4 mfma_bf16(short8 a, short8 b, floatx4 c) {
    return __builtin_amdgcn_mfma_f32_16x16x32_bf16(a, b, c, 0, 0, 0);
}

// ---------------- dtype detect: head_mask == 1.0 exactly.  bf16 word0 = 0x3F803F80, fp32 = 0x3F800000
__global__ void detect_k(const unsigned int* __restrict__ hm, int* __restrict__ flag) {
    if (threadIdx.x == 0) *flag = ((hm[0] & 0xFFFFu) != 0u) ? 1 : 0;  // 1 = inputs are bf16
}

// ---------------- canonicalize input -> bf16 buffer ----------------
__global__ void conv_k(const void* __restrict__ src, u16* __restrict__ dst, int n,
                       const int* __restrict__ flag) {
    int i = blockIdx.x * 256 + threadIdx.x;
    if (i < n) dst[i] = (*flag) ? ((const u16*)src)[i] : f2b(((const float*)src)[i]);
}

// ---------------- merged small-tensor converter (12 segments, layout = 'smalls') ----------------
struct SmallSrc { const void* p[12]; };
__global__ void convsmall_k(SmallSrc srcs, u16* __restrict__ dst, const int* __restrict__ flag) {
    const int offs[13] = {0, 1024, 2048, 3072, 4096, 8192, 9216, 10240, 11264, 12288, 13312, 17408, 17424};
    int i = blockIdx.x * 256 + threadIdx.x;
    if (i >= 17424) return;
    int seg = 0;
    while (i >= offs[seg + 1]) seg++;
    int off = i - offs[seg];
    const void* s = srcs.p[seg];
    dst[i] = (*flag) ? ((const u16*)s)[off] : f2b(((const float*)s)[off]);
}

// ---------------- fused convert + transpose: src [R,C] -> dst bf16 [C,R] ----------------
__global__ void convT_k(const void* __restrict__ src, u16* __restrict__ dst, int R, int C,
                        const int* __restrict__ flag) {
    __shared__ u16 t[32][33];
    int bx = blockIdx.x * 32, by = blockIdx.y * 32;
    int tx = threadIdx.x, ty = threadIdx.y;  // 32 x 8
    if (*flag) {
        const u16* s = (const u16*)src;
        for (int j = ty; j < 32; j += 8) t[j][tx] = s[(size_t)(by + j) * C + bx + tx];
    } else {
        const float* s = (const float*)src;
        for (int j = ty; j < 32; j += 8) t[j][tx] = f2b(s[(size_t)(by + j) * C + bx + tx]);
    }
    __syncthreads();
    for (int j = ty; j < 32; j += 8) dst[(size_t)(bx + j) * R + by + tx] = t[tx][j];
}

// ---------------- GEMM: C = A[M,K] @ Bt[N,K]^T + bias (canonical bf16) ----------------
// MODE 0: QKV concat store (N=3072): q,k -> [bh][s][d]; v (cols>=2048) -> TRANSPOSED [bh][d][s]
// MODE 1: out bf16 [M,N] = x + resid(bf16)[M,N]
// MODE 2: out bf16 [M,N] = gelu_exact(x)
template <int MODE>
__global__ __launch_bounds__(256, 2) void gemm_k(
    const u16* __restrict__ A, const u16* __restrict__ Bt,
    const u16* __restrict__ bias, const u16* __restrict__ resid,
    u16* __restrict__ Cout, int M, int N, int K) {
    __shared__ __align__(16) u16 As[128 * 40];
    __shared__ __align__(16) u16 Bs[128 * 40];
    const int m0 = blockIdx.x * 128, n0 = blockIdx.y * 128;
    const int tid = threadIdx.x;
    const int wave = tid >> 6, lane = tid & 63;
    const int wm = (wave >> 1) * 64, wn = (wave & 1) * 64;
    const int c = lane & 15, quad = lane >> 4;
    floatx4 acc[4][4] = {};
    for (int k0 = 0; k0 < K; k0 += 32) {
        __syncthreads();
        {
            int ch = tid, row = ch >> 2, kc = ch & 3;
            *(uint4*)&As[row * 40 + kc * 8] = *(const uint4*)&A[(size_t)(m0 + row) * K + k0 + kc * 8];
            *(uint4*)&Bs[row * 40 + kc * 8] = *(const uint4*)&Bt[(size_t)(n0 + row) * K + k0 + kc * 8];
            ch = tid + 256; row = ch >> 2; kc = ch & 3;
            *(uint4*)&As[row * 40 + kc * 8] = *(const uint4*)&A[(size_t)(m0 + row) * K + k0 + kc * 8];
            *(uint4*)&Bs[row * 40 + kc * 8] = *(const uint4*)&Bt[(size_t)(n0 + row) * K + k0 + kc * 8];
        }
        __syncthreads();
        short8 af[4], bf[4];
#pragma unroll
        for (int mi = 0; mi < 4; mi++) af[mi] = *(const short8*)&As[(wm + mi * 16 + c) * 40 + quad * 8];
#pragma unroll
        for (int ni = 0; ni < 4; ni++) bf[ni] = *(const short8*)&Bs[(wn + ni * 16 + c) * 40 + quad * 8];
#pragma unroll
        for (int mi = 0; mi < 4; mi++)
#pragma unroll
            for (int ni = 0; ni < 4; ni++)
                acc[mi][ni] = mfma_bf16(af[mi], bf[ni], acc[mi][ni]);
    }
#pragma unroll
    for (int ni = 0; ni < 4; ni++) {
        int col = n0 + wn + ni * 16 + c;
        float bv = b2f(bias[col]);
#pragma unroll
        for (int mi = 0; mi < 4; mi++) {
            int row0 = m0 + wm + mi * 16 + quad * 4;
            if (MODE == 0 && (col >> 10) == 2) {
                // V transposed store: vt[bh][d][s], 4 consecutive s -> ushort4
                int rem = col & 1023, h = rem >> 6, d = rem & 63;
                int bb = row0 >> 10, s = row0 & 1023;
                ushort4 pv;
                pv.x = f2b(acc[mi][ni][0] + bv); pv.y = f2b(acc[mi][ni][1] + bv);
                pv.z = f2b(acc[mi][ni][2] + bv); pv.w = f2b(acc[mi][ni][3] + bv);
                *(ushort4*)&Cout[(size_t)2 * 4194304 + ((size_t)(bb * 16 + h) * 64 + d) * 1024 + s] = pv;
            } else {
#pragma unroll
                for (int r = 0; r < 4; r++) {
                    int row = row0 + r;
                    float x = acc[mi][ni][r] + bv;
                    size_t idx = (size_t)row * N + col;
                    if (MODE == 0) {
                        int which = col >> 10, rem = col & 1023, h = rem >> 6, d = rem & 63;
                        int bb = row >> 10, s = row & 1023;
                        Cout[(size_t)which * 4194304 + ((size_t)(bb * 16 + h) * 1024 + s) * 64 + d] = f2b(x);
                    } else if (MODE == 1) {
                        Cout[idx] = f2b(x + b2f(resid[idx]));
                    } else {
                        float gl = 0.5f * x * (1.0f + erff(x * 0.70710678118654752f));
                        Cout[idx] = f2b(gl);
                    }
                }
            }
        }
    }
}

// ---------------- flash attention with relative_key_query bias (canonical bf16) ----------------
// q,k: [bh][s][64]; vt: [bh][d][s] (pre-transposed); de: [2047][64]; ctx out: [B,S,H,D]
// Round-4 skeleton (LDS staging, batch-issued loads) + vectorized VT staging, ushort4 band
// stores in transposed layout, 4 barriers/tile. LDS 62,464 B -> 2 blocks/CU.
__global__ __launch_bounds__(256, 2) void attn_k(
    const u16* __restrict__ q, const u16* __restrict__ k, const u16* __restrict__ vt,
    const u16* __restrict__ de, const u16* __restrict__ amask, const u16* __restrict__ hmask,
    u16* __restrict__ ctx) {
    __shared__ __align__(16) u16 U1[128 * 72];   // de band [128][72] ∪ { Ps [64][72] @0, VTs [64][72] @+4608 }
    __shared__ __align__(16) u16 Ks[64 * 72];    // K tile [r][d]
    __shared__ __align__(16) u16 QDT[128 * 68];  // qd band transposed [u][l]
    __shared__ __align__(16) u16 KDT[128 * 68];  // kd band transposed [u][r]
    const int bh = blockIdx.y, b = bh >> 4, h = bh & 15;
    const int L0 = blockIdx.x * 64;
    const int tid = threadIdx.x, wave = tid >> 6, lane = tid & 63;
    const int c = lane & 15, quad = lane >> 4;
    u16* Ps = U1;

    const size_t qrow = ((size_t)bh * 1024 + L0 + wave * 16 + c) * 64;
    const short8 qf0 = *(const short8*)&q[qrow + quad * 8];
    const short8 qf1 = *(const short8*)&q[qrow + 32 + quad * 8];
    const u16* kbase = k + (size_t)bh * 65536;
    const u16* vbase = vt + (size_t)bh * 65536;

    floatx4 O[4] = {};
    float mrow[4] = {-1e30f, -1e30f, -1e30f, -1e30f};
    float lrow[4] = {0.f, 0.f, 0.f, 0.f};
    const float hm = b2f(hmask[h]);

    for (int rt = 0; rt < 16; rt++) {
        const int R0 = rt * 64;
        const int t0 = L0 - R0 + 960;
        __syncthreads();  // (a) prev-tile PV finished reading Ps/VTs before staging overwrites
        // ---- stage K tile + de band (batch-issued uint4 -> LDS) ----
        {
            int ch = tid, row = ch >> 3, kc = ch & 7;
            *(uint4*)&Ks[row * 72 + kc * 8] = *(const uint4*)&kbase[(size_t)(R0 + row) * 64 + kc * 8];
            ch = tid + 256; row = ch >> 3; kc = ch & 7;
            *(uint4*)&Ks[row * 72 + kc * 8] = *(const uint4*)&kbase[(size_t)(R0 + row) * 64 + kc * 8];
        }
#pragma unroll
        for (int i = 0; i < 4; i++) {
            int ch = tid + i * 256, row = ch >> 3, kc = ch & 7;
            int tr = t0 + row; if (tr > 2046) tr = 2046;  // only u<=126 used; clamp avoids OOB
            *(uint4*)&U1[row * 72 + kc * 8] = *(const uint4*)&de[(size_t)tr * 64 + kc * 8];
        }
        __syncthreads();  // (b) staged
        // ---- qd/kd bands -> transposed LDS [u][l/r], ushort4 stores ----
        {
            const short8 ka0 = *(const short8*)&Ks[(wave * 16 + c) * 72 + quad * 8];
            const short8 ka1 = *(const short8*)&Ks[(wave * 16 + c) * 72 + 32 + quad * 8];
#pragma unroll
            for (int ut = 0; ut < 8; ut++) {
                const short8 df0 = *(const short8*)&U1[(ut * 16 + c) * 72 + quad * 8];
                const short8 df1 = *(const short8*)&U1[(ut * 16 + c) * 72 + 32 + quad * 8];
                floatx4 aq = {}, ak = {};
                aq = mfma_bf16(qf0, df0, aq); aq = mfma_bf16(qf1, df1, aq);
                ak = mfma_bf16(ka0, df0, ak); ak = mfma_bf16(ka1, df1, ak);
                ushort4 wq, wk;
                wq.x = f2b(aq[0]); wq.y = f2b(aq[1]); wq.z = f2b(aq[2]); wq.w = f2b(aq[3]);
                wk.x = f2b(ak[0]); wk.y = f2b(ak[1]); wk.z = f2b(ak[2]); wk.w = f2b(ak[3]);
                int base = (ut * 16 + c) * 68 + wave * 16 + quad * 4;
                *(ushort4*)&QDT[base] = wq;
                *(ushort4*)&KDT[base] = wk;
            }
        }
        __syncthreads();  // (c) bands ready; de region now dead
        // ---- phase C: issue VT staging loads, compute S + softmax, write P, write VT ----
        uint4 vstage0, vstage1;
        {
            int ch = tid, d0 = ch >> 3, kc0 = ch & 7;
            vstage0 = *(const uint4*)&vbase[(size_t)d0 * 1024 + R0 + kc0 * 8];
            int ch1 = tid + 256, d1 = ch1 >> 3, kc1 = ch1 & 7;
            vstage1 = *(const uint4*)&vbase[(size_t)d1 * 1024 + R0 + kc1 * 8];
        }
        float sv[4][4];
#pragma unroll
        for (int nt = 0; nt < 4; nt++) {
            floatx4 a = {};
            a = mfma_bf16(qf0, *(const short8*)&Ks[(nt * 16 + c) * 72 + quad * 8], a);
            a = mfma_bf16(qf1, *(const short8*)&Ks[(nt * 16 + c) * 72 + 32 + quad * 8], a);
            int ri = nt * 16 + c;
            float am = b2f(amask[b * 1024 + R0 + ri]);
#pragma unroll
            for (int r = 0; r < 4; r++) {
                int li = wave * 16 + quad * 4 + r;
                int u = li - ri + 63;  // in [0,126]
                float biasv = b2f(QDT[u * 68 + li]) + b2f(KDT[u * 68 + ri]);
                sv[nt][r] = (a[r] + biasv) * 0.125f + am;
            }
        }
        // ---- online softmax (rows spread over the 16 lanes of each quad-group) ----
#pragma unroll
        for (int r = 0; r < 4; r++) {
            float rmax = fmaxf(fmaxf(sv[0][r], sv[1][r]), fmaxf(sv[2][r], sv[3][r]));
#pragma unroll
            for (int m = 1; m < 16; m <<= 1) rmax = fmaxf(rmax, __shfl_xor(rmax, m, 64));
            float mnew = fmaxf(mrow[r], rmax);
            float alpha = __expf(mrow[r] - mnew);
            float ps = 0.f;
#pragma unroll
            for (int nt = 0; nt < 4; nt++) { float p = __expf(sv[nt][r] - mnew); sv[nt][r] = p; ps += p; }
#pragma unroll
            for (int m = 1; m < 16; m <<= 1) ps += __shfl_xor(ps, m, 64);
            lrow[r] = lrow[r] * alpha + ps;
            mrow[r] = mnew;
            O[0][r] *= alpha; O[1][r] *= alpha; O[2][r] *= alpha; O[3][r] *= alpha;
        }
        // ---- write P (over dead de rows 0..63) ----
#pragma unroll
        for (int nt = 0; nt < 4; nt++)
#pragma unroll
            for (int r = 0; r < 4; r++)
                Ps[(wave * 16 + quad * 4 + r) * 72 + nt * 16 + c] = f2b(sv[nt][r]);
        // ---- write VT tile (over dead de rows 64..127), vectorized ----
        {
            int ch = tid, d0 = ch >> 3, kc0 = ch & 7;
            *(uint4*)&U1[4608 + d0 * 72 + kc0 * 8] = vstage0;
            int ch1 = tid + 256, d1 = ch1 >> 3, kc1 = ch1 & 7;
            *(uint4*)&U1[4608 + d1 * 72 + kc1 * 8] = vstage1;
        }
        __syncthreads();  // (d) P + VT ready
        // ---- O += P @ V ----
        {
            const short8 pa0 = *(const short8*)&Ps[(wave * 16 + c) * 72 + quad * 8];
            const short8 pa1 = *(const short8*)&Ps[(wave * 16 + c) * 72 + 32 + quad * 8];
#pragma unroll
            for (int dt = 0; dt < 4; dt++) {
                O[dt] = mfma_bf16(pa0, *(const short8*)&U1[4608 + (dt * 16 + c) * 72 + quad * 8], O[dt]);
                O[dt] = mfma_bf16(pa1, *(const short8*)&U1[4608 + (dt * 16 + c) * 72 + 32 + quad * 8], O[dt]);
            }
        }
    }
    // epilogue: ctx[b, s, h, d]
#pragma unroll
    for (int r = 0; r < 4; r++) {
        float inv = hm / lrow[r];
        int s = L0 + wave * 16 + quad * 4 + r;
#pragma unroll
        for (int dt = 0; dt < 4; dt++)
            ctx[(((size_t)b * 1024 + s) * 16 + h) * 64 + dt * 16 + c] = f2b(O[dt][r] * inv);
    }
}

// ---------------- LayerNorm over 1024 bf16 -> bf16 (FINAL: d_out, dtype per flag) ----------------
template <int FINAL>
__global__ __launch_bounds__(256) void ln_k(const u16* __restrict__ x, const u16* __restrict__ g,
                                            const u16* __restrict__ bb, void* __restrict__ out,
                                            const int* __restrict__ flag) {
    const int row = blockIdx.x, tid = threadIdx.x;
    const u16* xr = x + (size_t)row * 1024;
    float vv[4];
#pragma unroll
    for (int j = 0; j < 4; j++) vv[j] = b2f(xr[tid * 4 + j]);
    float s = vv[0] + vv[1] + vv[2] + vv[3];
    float ss = vv[0] * vv[0] + vv[1] * vv[1] + vv[2] * vv[2] + vv[3] * vv[3];
#pragma unroll
    for (int m = 1; m < 64; m <<= 1) { s += __shfl_xor(s, m, 64); ss += __shfl_xor(ss, m, 64); }
    __shared__ float red[8];
    int wave = tid >> 6, lane = tid & 63;
    if (lane == 0) { red[wave] = s; red[wave + 4] = ss; }
    __syncthreads();
    s = red[0] + red[1] + red[2] + red[3];
    ss = red[4] + red[5] + red[6] + red[7];
    float mu = s * (1.f / 1024.f);
    float var = ss * (1.f / 1024.f) - mu * mu;
    float rs = rsqrtf(var + 1e-12f);
    const int out_bf16 = FINAL ? *flag : 1;
#pragma unroll
    for (int j = 0; j < 4; j++) {
        int idx = tid * 4 + j;
        float val = (vv[j] - mu) * rs * b2f(g[idx]) + b2f(bb[idx]);
        if (out_bf16) ((u16*)out)[(size_t)row * 1024 + idx] = f2b(val);
        else          ((float*)out)[(size_t)row * 1024 + idx] = val;
    }
}

extern "C" void kernel_launch(void* const* d_in, const int* in_sizes, int n_in,
                              void* d_out, int out_size, void* d_ws, size_t ws_size,
                              hipStream_t stream) {
    (void)in_sizes; (void)n_in; (void)out_size;
    const void* hidden = d_in[0];
    const void* amaskI = d_in[1];
    const void* hmaskI = d_in[2];
    const void* Wq = d_in[3];  const void* bq = d_in[4];
    const void* Wk = d_in[5];  const void* bk = d_in[6];
    const void* Wv = d_in[7];  const void* bv = d_in[8];
    const void* de = d_in[9];
    const void* Wo = d_in[10]; const void* bo = d_in[11];
    const void* ln1g = d_in[12]; const void* ln1b = d_in[13];
    const void* Wi = d_in[14]; const void* bi = d_in[15];
    const void* Wo2 = d_in[16]; const void* bo2 = d_in[17];
    const void* ln2g = d_in[18]; const void* ln2b = d_in[19];

    const size_t MB = 1048576;
    char* ws = (char*)d_ws;
    const bool big = (ws_size >= (size_t)70 * MB);

    u16* wsQKV  = (u16*)(ws);                      // Q@0, K@+4M elts, V^T@+8M elts
    u16* wsCtx  = (u16*)(ws + 24 * MB);
    u16* wsInter= (u16*)(ws);                      // full path: 32MB over QKV+Ctx
    u16* cHid   = (u16*)(ws + 32 * MB);
    u16* cWo2T  = (u16*)(ws + 32 * MB);            // after cHid dead
    u16* preLN  = big ? (u16*)(ws + 40 * MB) : (u16*)(ws + 16 * MB);
    u16* attnO  = big ? (u16*)(ws + 48 * MB) : (u16*)(ws + 24 * MB);
    u16* cQKVT  = big ? (u16*)(ws + 56 * MB) : (u16*)(ws + 40 * MB);
    u16* cWoT   = big ? (u16*)(ws + 62 * MB) : (u16*)(ws + 46 * MB);
    u16* cWiT   = cQKVT;                           // 8MB over cQKVT+cWoT after both dead
    u16* cDe    = big ? (u16*)(ws + 64 * MB) : (u16*)(ws + 48 * MB);
    u16* smalls = (u16*)((char*)cDe + 262144);
    int* flag   = (int*)((char*)smalls + 65536);

    u16* s_bqkv = smalls;                 // 3072
    u16* s_bo   = smalls + 3072;          // 1024
    u16* s_bi   = smalls + 4096;          // 4096
    u16* s_bo2  = smalls + 8192;          // 1024
    u16* s_l1g  = smalls + 9216, *s_l1b = smalls + 10240;
    u16* s_l2g  = smalls + 11264, *s_l2b = smalls + 12288;
    u16* s_am   = smalls + 13312;         // 4096
    u16* s_hm   = smalls + 17408;         // 16

    detect_k<<<1, 64, 0, stream>>>((const unsigned int*)hmaskI, flag);

    auto conv = [&](const void* src, u16* dst, int n) {
        conv_k<<<(n + 255) / 256, 256, 0, stream>>>(src, dst, n, flag);
    };
    auto convT = [&](const void* src, u16* dst, int R, int C) {
        convT_k<<<dim3(C / 32, R / 32), dim3(32, 8), 0, stream>>>(src, dst, R, C, flag);
    };

    conv(hidden, cHid, 4194304);
    convT(Wq, cQKVT, 1024, 1024);
    convT(Wk, cQKVT + 1048576, 1024, 1024);
    convT(Wv, cQKVT + 2097152, 1024, 1024);
    convT(Wo, cWoT, 1024, 1024);
    conv(de, cDe, 2047 * 64);
    {
        SmallSrc st;
        st.p[0] = bq;   st.p[1] = bk;   st.p[2] = bv;   st.p[3] = bo;
        st.p[4] = bi;   st.p[5] = bo2;  st.p[6] = ln1g; st.p[7] = ln1b;
        st.p[8] = ln2g; st.p[9] = ln2b; st.p[10] = amaskI; st.p[11] = hmaskI;
        convsmall_k<<<(17424 + 255) / 256, 256, 0, stream>>>(st, smalls, flag);
    }

    // fused QKV projection -> Q,K [bh][s][d]; V^T [bh][d][s]
    gemm_k<0><<<dim3(32, 24), 256, 0, stream>>>(cHid, cQKVT, s_bqkv, nullptr, wsQKV, 4096, 3072, 1024);

    // attention -> ctx [B,S,H,D]
    attn_k<<<dim3(16, 64), 256, 0, stream>>>(wsQKV, wsQKV + 4194304, wsQKV + 8388608,
                                             cDe, s_am, s_hm, wsCtx);

    // ctx @ Wo + bo + hidden -> preLN
    gemm_k<1><<<dim3(32, 8), 256, 0, stream>>>(wsCtx, cWoT, s_bo, cHid, preLN, 4096, 1024, 1024);

    // FF weights into now-dead regions
    convT(Wi, cWiT, 1024, 4096);    // WiT [4096,1024]
    convT(Wo2, cWo2T, 4096, 1024);  // Wo2T [1024,4096]

    // LN1 -> attnO
    ln_k<0><<<4096, 256, 0, stream>>>(preLN, s_l1g, s_l1b, attnO, flag);

    if (big) {
        gemm_k<2><<<dim3(32, 32), 256, 0, stream>>>(attnO, cWiT, s_bi, nullptr, wsInter, 4096, 4096, 1024);
        gemm_k<1><<<dim3(32, 8), 256, 0, stream>>>(wsInter, cWo2T, s_bo2, attnO, preLN, 4096, 1024, 4096);
    } else {
        u16* strip = (u16*)(ws);  // 2048x4096 bf16 = 16MB over dead Q|K
        for (int s = 0; s < 2; s++) {
            const u16* aoff = attnO + (size_t)s * 2048 * 1024;
            gemm_k<2><<<dim3(16, 32), 256, 0, stream>>>(aoff, cWiT, s_bi, nullptr, strip, 2048, 4096, 1024);
            gemm_k<1><<<dim3(16, 8), 256, 0, stream>>>(strip, cWo2T, s_bo2, aoff,
                                                       preLN + (size_t)s * 2048 * 1024, 2048, 1024, 4096);
        }
    }

    // LN2 -> d_out (dtype per flag)
    ln_k<1><<<4096, 256, 0, stream>>>(preLN, s_l2g, s_l2b, d_out, flag);
}